// Round 2
// baseline (795.970 us; speedup 1.0000x reference)
//
#include <hip/hip_runtime.h>
#include <math.h>

typedef _Float16 f16x8 __attribute__((ext_vector_type(8)));
typedef _Float16 f16x2 __attribute__((ext_vector_type(2)));
typedef float    f32x4 __attribute__((ext_vector_type(4)));

// Fixed ECG graph: neighbor bitmasks and degrees (a_eff = adj + 2I, deg = rowsum).
namespace {
constexpr unsigned kMask[12] = {0x01Eu,0x03Du,0x02Bu,0x007u,0x003u,0x006u,
                                0x080u,0x140u,0x280u,0x500u,0xA00u,0x400u};
constexpr int kDeg[12] = {6,7,6,5,4,4,3,4,4,4,4,3};

constexpr int AST = 72;                    // A/W LDS row stride in halves (16B aligned)
constexpr int HST = 260;                   // hidden-state LDS row stride in halves
constexpr int ABYTES = 96  * AST * 2;      // 13824
constexpr int WBYTES = 256 * AST * 2;      // 36864
constexpr int HBYTES = 96  * HST * 2;      // 49920
constexpr int SMEM   = ABYTES + WBYTES + HBYTES;   // 100608 B -> 1 block/CU
}

// LDS-only fence + raw barrier: prefetch global loads (vmcnt) stay in flight
// across the barrier (unlike __syncthreads(), which drains vmcnt(0)).
__device__ __forceinline__ void barrier_keep_vmcnt()
{
    __builtin_amdgcn_sched_barrier(0);
    asm volatile("s_waitcnt lgkmcnt(0)" ::: "memory");
    __builtin_amdgcn_s_barrier();
    __builtin_amdgcn_sched_barrier(0);
}

// One GCN matmul: acc(96xN) += A_norm-mixed(src) @ W. src is global fp32 x
// (layer 1) or LDS fp16 hidden state (layers 2/3). 512 threads: waves 0-3 run
// the 12x12 lead mix while staging A, waves 4-7 stage W^T; all 8 waves MFMA.
// Next-chunk x/W loads are issued into registers before the barrier (1-deep
// prefetch across the non-draining barrier).
template<int K, int N, bool SRC_LDS>
__device__ __forceinline__ void run_layer(
    const float*    __restrict__ xg,     // global fp32 src (layer 1)
    const _Float16* __restrict__ hs,     // LDS fp16 src (layers 2/3)
    const _Float16* __restrict__ wt,     // W^T, N x K row-major fp16 (global)
    _Float16* __restrict__ Abuf,
    _Float16* __restrict__ Wbuf,
    long rowbase, int tid,
    f32x4 (&acc)[3][N/64])
{
    constexpr int NT = N / 64, KC = K / 64, NPASS = N / 32;
    const int lane = tid & 63, wave = tid >> 6;
    const int wm = wave & 1, wn = wave >> 1;
    const int l15 = lane & 15, q = lane >> 4;

    float dinv[12];
    #pragma unroll
    for (int r = 0; r < 12; ++r) dinv[r] = 1.0f / sqrtf((float)kDeg[r]);

    #pragma unroll
    for (int a = 0; a < 3; ++a)
        #pragma unroll
        for (int b = 0; b < NT; ++b)
            acc[a][b] = (f32x4){0.f, 0.f, 0.f, 0.f};

    const int g  = tid >> 5, f2 = tid & 31;                  // mix role (tid<256)
    const int t2 = tid - 256, k8 = t2 & 7, orow = t2 >> 3;   // W role (tid>=256)

    float2 y[12];
    uint4  wreg[NPASS];

    // Preload chunk 0 into registers.
    if (tid < 256) {
        if constexpr (!SRC_LDS) {
            #pragma unroll
            for (int n = 0; n < 12; ++n) {
                const float* p = xg + (rowbase + g*12 + n) * (long)K + f2*2;
                y[n].x = p[0]; y[n].y = p[1];
            }
        }
    } else {
        #pragma unroll
        for (int pass = 0; pass < NPASS; ++pass)
            wreg[pass] = *(const uint4*)(wt + (long)(pass*32 + orow) * K + k8*8);
    }

    for (int kc = 0; kc < KC; ++kc) {
        if (tid < 256) {
            if constexpr (SRC_LDS) {
                #pragma unroll
                for (int n = 0; n < 12; ++n) {
                    const f16x2 h2 = *(const f16x2*)&hs[(g*12 + n)*HST + kc*64 + f2*2];
                    y[n].x = (float)h2.x; y[n].y = (float)h2.y;
                }
            }
            float2 ys[12];
            #pragma unroll
            for (int n = 0; n < 12; ++n) {
                ys[n].x = dinv[n] * y[n].x;
                ys[n].y = dinv[n] * y[n].y;
            }
            #pragma unroll
            for (int r = 0; r < 12; ++r) {
                float sx = 2.0f * ys[r].x;       // self-loop weight 2
                float sy = 2.0f * ys[r].y;
                #pragma unroll
                for (int j = 0; j < 12; ++j)
                    if ((kMask[r] >> j) & 1u) { sx += ys[j].x; sy += ys[j].y; }
                sx *= dinv[r]; sy *= dinv[r];
                f16x2 h2; h2.x = (_Float16)sx; h2.y = (_Float16)sy;
                *(f16x2*)&Abuf[(g*12 + r)*AST + f2*2] = h2;
            }
            if constexpr (!SRC_LDS) {
                if (kc + 1 < KC) {               // prefetch next x chunk
                    #pragma unroll
                    for (int n = 0; n < 12; ++n) {
                        const float* p = xg + (rowbase + g*12 + n) * (long)K
                                            + (kc + 1)*64 + f2*2;
                        y[n].x = p[0]; y[n].y = p[1];
                    }
                }
            }
        } else {
            #pragma unroll
            for (int pass = 0; pass < NPASS; ++pass)
                *(uint4*)&Wbuf[(pass*32 + orow)*AST + k8*8] = wreg[pass];
            if (kc + 1 < KC) {                   // prefetch next W chunk
                #pragma unroll
                for (int pass = 0; pass < NPASS; ++pass)
                    wreg[pass] = *(const uint4*)(wt + (long)(pass*32 + orow) * K
                                                    + (kc + 1)*64 + k8*8);
            }
        }
        barrier_keep_vmcnt();

        #pragma unroll
        for (int ks = 0; ks < 2; ++ks) {         // two 16x16x32 k-steps per chunk
            f16x8 af[3], bf[NT];
            #pragma unroll
            for (int tm = 0; tm < 3; ++tm)
                af[tm] = *(const f16x8*)&Abuf[(wm*48 + tm*16 + l15)*AST + ks*32 + q*8];
            #pragma unroll
            for (int tn = 0; tn < NT; ++tn)
                bf[tn] = *(const f16x8*)&Wbuf[(wn*NT*16 + tn*16 + l15)*AST + ks*32 + q*8];
            #pragma unroll
            for (int tm = 0; tm < 3; ++tm)
                #pragma unroll
                for (int tn = 0; tn < NT; ++tn)
                    acc[tm][tn] = __builtin_amdgcn_mfma_f32_16x16x32_f16(
                        af[tm], bf[tn], acc[tm][tn], 0, 0, 0);
        }
        barrier_keep_vmcnt();
    }
}

// bias + relu, store fp16 hidden state into LDS.
template<int N>
__device__ __forceinline__ void store_h(
    f32x4 (&acc)[3][N/64], const float* __restrict__ bias,
    _Float16* __restrict__ H, int tid)
{
    constexpr int NT = N / 64;
    const int lane = tid & 63, wave = tid >> 6;
    const int wm = wave & 1, wn = wave >> 1;
    const int l15 = lane & 15, q = lane >> 4;
    float bcol[NT];
    #pragma unroll
    for (int tn = 0; tn < NT; ++tn) bcol[tn] = bias[wn*NT*16 + tn*16 + l15];
    #pragma unroll
    for (int tm = 0; tm < 3; ++tm)
        #pragma unroll
        for (int tn = 0; tn < NT; ++tn)
            #pragma unroll
            for (int r = 0; r < 4; ++r) {
                const int row = wm*48 + tm*16 + q*4 + r;
                const int col = wn*NT*16 + tn*16 + l15;
                H[row*HST + col] = (_Float16)fmaxf(acc[tm][tn][r] + bcol[tn], 0.f);
            }
}

// Fully fused 3-layer GCN + pool: hidden states never touch HBM.
// Block = 96 rows (8 batch groups of 12 leads), grid 2048.
__global__ __launch_bounds__(512)
void gcn_fused(const float* __restrict__ x,
               const _Float16* __restrict__ wt1, const float* __restrict__ b1,
               const _Float16* __restrict__ wt2, const float* __restrict__ b2,
               const _Float16* __restrict__ wt3, const float* __restrict__ b3,
               float* __restrict__ out)
{
    __shared__ __align__(16) char smem[SMEM];
    _Float16* Abuf = (_Float16*)smem;
    _Float16* Wbuf = (_Float16*)(smem + ABYTES);
    _Float16* Hbuf = (_Float16*)(smem + ABYTES + WBYTES);

    const int tid = threadIdx.x;
    const long rowbase = (long)blockIdx.x * 96;

    f32x4 acc[3][4];
    run_layer<512, 256, false>(x, nullptr, wt1, Abuf, Wbuf, rowbase, tid, acc);
    store_h<256>(acc, b1, Hbuf, tid);
    __syncthreads();

    run_layer<256, 256, true>(nullptr, Hbuf, wt2, Abuf, Wbuf, rowbase, tid, acc);
    store_h<256>(acc, b2, Hbuf, tid);
    __syncthreads();

    f32x4 acc3[3][2];
    run_layer<256, 128, true>(nullptr, Hbuf, wt3, Abuf, Wbuf, rowbase, tid, acc3);

    // Pool mean/max over the 12 leads of each batch group. Staging buffers are
    // dead after the final barrier -> reuse smem as float C[96][129].
    float* C = (float*)smem;
    {
        const int lane = tid & 63, wave = tid >> 6;
        const int wm = wave & 1, wn = wave >> 1;
        const int l15 = lane & 15, q = lane >> 4;
        #pragma unroll
        for (int tm = 0; tm < 3; ++tm)
            #pragma unroll
            for (int tn = 0; tn < 2; ++tn)
                #pragma unroll
                for (int r = 0; r < 4; ++r) {
                    const int row = wm*48 + tm*16 + q*4 + r;
                    const int col = wn*32 + tn*16 + l15;
                    C[row*129 + col] = acc3[tm][tn][r];
                }
    }
    __syncthreads();
    #pragma unroll
    for (int p = 0; p < 2; ++p) {
        const int idx = tid + p*512;           // 8 groups x 128 cols = 1024
        const int bl  = idx >> 7;
        const int col = idx & 127;
        float s = 0.0f, mx = -INFINITY;
        #pragma unroll
        for (int n = 0; n < 12; ++n) {
            const float v = C[(bl*12 + n)*129 + col];
            s += v; mx = fmaxf(mx, v);
        }
        const float b  = b3[col];
        const long  ob = ((long)blockIdx.x*8 + bl) * 256;
        out[ob + col]       = s / 12.0f + b;   // bias after pool: valid for mean & max
        out[ob + 128 + col] = mx + b;
    }
}

// Convert W1/W2/W3 (fp32, K x N) to fp16 transposed (N x K) in workspace.
__global__ void prep_weights(const float* __restrict__ W1,
                             const float* __restrict__ W2,
                             const float* __restrict__ W3,
                             _Float16* __restrict__ wt)
{
    const int tid = blockIdx.x * 256 + threadIdx.x;
    constexpr int N1 = 512*256, N2 = 256*256, N3 = 256*128;
    if (tid < N1) {
        const int o = tid >> 9, k = tid & 511;          // wt1: 256 x 512
        wt[tid] = (_Float16)W1[k*256 + o];
    } else if (tid < N1 + N2) {
        const int t = tid - N1;
        const int o = t >> 8, k = t & 255;              // wt2: 256 x 256
        wt[N1 + t] = (_Float16)W2[k*256 + o];
    } else if (tid < N1 + N2 + N3) {
        const int t = tid - N1 - N2;
        const int o = t >> 8, k = t & 255;              // wt3: 128 x 256
        wt[N1 + N2 + t] = (_Float16)W3[k*128 + o];      // W3 is (256,128): stride 128
    }
}

extern "C" void kernel_launch(void* const* d_in, const int* in_sizes, int n_in,
                              void* d_out, int out_size, void* d_ws, size_t ws_size,
                              hipStream_t stream)
{
    const float* x  = (const float*)d_in[0];
    const float* W1 = (const float*)d_in[1];
    const float* b1 = (const float*)d_in[2];
    const float* W2 = (const float*)d_in[3];
    const float* b2 = (const float*)d_in[4];
    const float* W3 = (const float*)d_in[5];
    const float* b3 = (const float*)d_in[6];
    float* out = (float*)d_out;

    // ws layout (halves): wt1 | wt2 | wt3   (hidden states now live in LDS)
    _Float16* wt  = (_Float16*)d_ws;
    _Float16* wt1 = wt;
    _Float16* wt2 = wt + 512*256;
    _Float16* wt3 = wt + 512*256 + 256*256;

    prep_weights<<<896, 256, 0, stream>>>(W1, W2, W3, wt);
    gcn_fused<<<2048, 512, 0, stream>>>(x, wt1, b1, wt2, b2, wt3, b3, out);
}

// Round 3
// 745.532 us; speedup vs baseline: 1.0677x; 1.0677x over previous
//
#include <hip/hip_runtime.h>
#include <math.h>

typedef _Float16 f16x8 __attribute__((ext_vector_type(8)));
typedef _Float16 f16x2 __attribute__((ext_vector_type(2)));
typedef float    f32x4 __attribute__((ext_vector_type(4)));

// Fixed ECG graph: neighbor bitmasks (self excluded) and dinv = 1/sqrt(deg).
namespace {
constexpr unsigned kMask[12] = {0x01Eu,0x03Du,0x02Bu,0x007u,0x003u,0x006u,
                                0x080u,0x140u,0x280u,0x500u,0xA00u,0x400u};
constexpr float kDinv[12] = {
    0.40824829046386302f, 0.37796447300922720f, 0.40824829046386302f,
    0.44721359549995794f, 0.5f, 0.5f,
    0.57735026918962576f, 0.5f, 0.5f, 0.5f, 0.5f, 0.57735026918962576f};

constexpr int ROWS = 48;                   // 4 lead-groups of 12 per block
constexpr int AST  = 72;                   // A-tile stride in halves (9x16B -> conflict-free b128)
constexpr int HST  = 258;                  // hidden stride in halves
constexpr int ABYTES = ROWS * AST * 2;     // 6912
constexpr int HBYTES = ROWS * HST * 2;     // 24768
constexpr int SMEM   = ABYTES + HBYTES;    // 31680 B -> >=2 blocks/CU; pool C (24768 B) fits
}

// LDS-only fence + raw barrier: global prefetch loads (vmcnt) stay in flight
// across the barrier (unlike __syncthreads(), which drains vmcnt(0)).
__device__ __forceinline__ void barrier_keep_vmcnt()
{
    __builtin_amdgcn_sched_barrier(0);
    asm volatile("s_waitcnt lgkmcnt(0)" ::: "memory");
    __builtin_amdgcn_s_barrier();
    __builtin_amdgcn_sched_barrier(0);
}

// Mix 3 output rows (R0..R0+2) of one lead-group from pre-scaled y, store fp16
// into Abuf. R0 is a template constant so kMask/kDinv fold at compile time.
template<int R0>
__device__ __forceinline__ void mix_rows(const float2 (&y)[12],
                                         _Float16* __restrict__ Abuf,
                                         int g, int f2)
{
    #pragma unroll
    for (int i = 0; i < 3; ++i) {
        const int r = R0 + i;
        float sx = 2.0f * y[r].x;          // self-loop weight 2
        float sy = 2.0f * y[r].y;
        #pragma unroll
        for (int j = 0; j < 12; ++j)
            if ((kMask[r] >> j) & 1u) { sx += y[j].x; sy += y[j].y; }
        sx *= kDinv[r]; sy *= kDinv[r];
        f16x2 h2; h2.x = (_Float16)sx; h2.y = (_Float16)sy;
        *(f16x2*)&Abuf[(g*12 + r)*AST + f2*2] = h2;
    }
}

// One GCN matmul: acc(48xN) += A_norm-mixed(src) @ W. src is global fp32 x
// (layer 1, with 1-deep register prefetch) or LDS fp16 hidden state.
// W fragments are loaded directly from global (L2-resident) into registers:
// no W staging, no wreg spill. bf loads issue FIRST each chunk so the
// compiler's wait-for-bf (vmcnt(N), ordered) leaves the x prefetch in flight.
// 8 waves each own N/8 output columns over all 48 rows.
template<int K, int N, bool SRC_LDS>
__device__ __forceinline__ void run_layer(
    const float*    __restrict__ xg,
    const _Float16* __restrict__ hs,
    const _Float16* __restrict__ wt,     // W^T, N x K row-major fp16 (global)
    _Float16* __restrict__ Abuf,
    long rowbase, int tid,
    f32x4 (&acc)[3][N/128])
{
    constexpr int NT = N / 128, KC = K / 64;
    const int lane = tid & 63, wave = tid >> 6;
    const int l15 = lane & 15, q = lane >> 4;
    const int g   = (tid >> 5) & 3;        // lead-group 0..3
    const int f2  = tid & 31;              // float2 column within 64-col chunk
    const int qtr = tid >> 7;              // wave-uniform row-quarter 0..3

    #pragma unroll
    for (int a = 0; a < 3; ++a)
        #pragma unroll
        for (int b = 0; b < NT; ++b)
            acc[a][b] = (f32x4){0.f, 0.f, 0.f, 0.f};

    float2 y[12];                          // pre-scaled (dinv*val) lead values
    if constexpr (!SRC_LDS) {
        #pragma unroll
        for (int n = 0; n < 12; ++n) {
            const float* p = xg + (rowbase + g*12 + n) * (long)K + f2*2;
            y[n].x = kDinv[n] * p[0]; y[n].y = kDinv[n] * p[1];
        }
    }

    for (int kc = 0; kc < KC; ++kc) {
        // 1) W fragments for this chunk: issued first (oldest in vmcnt queue).
        f16x8 bf[2][NT];
        #pragma unroll
        for (int ks = 0; ks < 2; ++ks)
            #pragma unroll
            for (int tn = 0; tn < NT; ++tn)
                bf[ks][tn] = *(const f16x8*)(wt
                    + (long)(wave*NT*16 + tn*16 + l15) * K
                    + kc*64 + ks*32 + q*8);

        // 2) Lead-mix this chunk into Abuf.
        if constexpr (SRC_LDS) {
            #pragma unroll
            for (int n = 0; n < 12; ++n) {
                const f16x2 h2 = *(const f16x2*)&hs[(g*12 + n)*HST + kc*64 + f2*2];
                y[n].x = kDinv[n] * (float)h2.x;
                y[n].y = kDinv[n] * (float)h2.y;
            }
        }
        switch (qtr) {                      // wave-uniform branch
            case 0:  mix_rows<0>(y, Abuf, g, f2); break;
            case 1:  mix_rows<3>(y, Abuf, g, f2); break;
            case 2:  mix_rows<6>(y, Abuf, g, f2); break;
            default: mix_rows<9>(y, Abuf, g, f2); break;
        }

        // 3) Layer-1: prefetch next x chunk (scaled) — stays in flight across
        //    the non-draining barrier and the bf vmcnt waits.
        if constexpr (!SRC_LDS) {
            if (kc + 1 < KC) {
                #pragma unroll
                for (int n = 0; n < 12; ++n) {
                    const float* p = xg + (rowbase + g*12 + n) * (long)K
                                        + (kc + 1)*64 + f2*2;
                    y[n].x = kDinv[n] * p[0]; y[n].y = kDinv[n] * p[1];
                }
            }
        }
        barrier_keep_vmcnt();

        // 4) MFMA: A fragments from LDS, W fragments already in registers.
        #pragma unroll
        for (int ks = 0; ks < 2; ++ks) {
            f16x8 af[3];
            #pragma unroll
            for (int tm = 0; tm < 3; ++tm)
                af[tm] = *(const f16x8*)&Abuf[(tm*16 + l15)*AST + ks*32 + q*8];
            #pragma unroll
            for (int tm = 0; tm < 3; ++tm)
                #pragma unroll
                for (int tn = 0; tn < NT; ++tn)
                    acc[tm][tn] = __builtin_amdgcn_mfma_f32_16x16x32_f16(
                        af[tm], bf[ks][tn], acc[tm][tn], 0, 0, 0);
        }
        barrier_keep_vmcnt();
    }
}

// bias + relu, store fp16 hidden state into LDS.
template<int N>
__device__ __forceinline__ void store_h(
    f32x4 (&acc)[3][N/128], const float* __restrict__ bias,
    _Float16* __restrict__ H, int tid)
{
    constexpr int NT = N / 128;
    const int lane = tid & 63, wave = tid >> 6;
    const int l15 = lane & 15, q = lane >> 4;
    float bcol[NT];
    #pragma unroll
    for (int tn = 0; tn < NT; ++tn) bcol[tn] = bias[wave*NT*16 + tn*16 + l15];
    #pragma unroll
    for (int tm = 0; tm < 3; ++tm)
        #pragma unroll
        for (int tn = 0; tn < NT; ++tn)
            #pragma unroll
            for (int r = 0; r < 4; ++r) {
                const int row = tm*16 + q*4 + r;
                const int col = wave*NT*16 + tn*16 + l15;
                H[row*HST + col] = (_Float16)fmaxf(acc[tm][tn][r] + bcol[tn], 0.f);
            }
}

// Fully fused 3-layer GCN + pool; hidden states live in LDS.
// Block = 48 rows (4 batch groups of 12 leads), grid 4096, 8 waves.
__global__ __launch_bounds__(512, 4)
void gcn_fused(const float* __restrict__ x,
               const _Float16* __restrict__ wt1, const float* __restrict__ b1,
               const _Float16* __restrict__ wt2, const float* __restrict__ b2,
               const _Float16* __restrict__ wt3, const float* __restrict__ b3,
               float* __restrict__ out)
{
    __shared__ __align__(16) char smem[SMEM];
    _Float16* Abuf = (_Float16*)smem;
    _Float16* Hbuf = (_Float16*)(smem + ABYTES);

    const int tid = threadIdx.x;
    const long rowbase = (long)blockIdx.x * ROWS;

    f32x4 acc[3][2];
    run_layer<512, 256, false>(x, nullptr, wt1, Abuf, rowbase, tid, acc);
    store_h<256>(acc, b1, Hbuf, tid);
    __syncthreads();

    run_layer<256, 256, true>(nullptr, Hbuf, wt2, Abuf, rowbase, tid, acc);
    store_h<256>(acc, b2, Hbuf, tid);
    __syncthreads();

    f32x4 acc3[3][1];
    run_layer<256, 128, true>(nullptr, Hbuf, wt3, Abuf, rowbase, tid, acc3);

    // Pool mean/max over the 12 leads of each batch group. Staging buffers are
    // dead after the final barrier -> reuse smem as float C[48][129].
    float* C = (float*)smem;
    {
        const int lane = tid & 63, wave = tid >> 6;
        const int l15 = lane & 15, q = lane >> 4;
        #pragma unroll
        for (int tm = 0; tm < 3; ++tm)
            #pragma unroll
            for (int r = 0; r < 4; ++r) {
                const int row = tm*16 + q*4 + r;
                const int col = wave*16 + l15;
                C[row*129 + col] = acc3[tm][0][r];
            }
    }
    __syncthreads();
    {
        const int bl  = tid >> 7;              // batch group 0..3
        const int col = tid & 127;
        float s = 0.0f, mx = -INFINITY;
        #pragma unroll
        for (int n = 0; n < 12; ++n) {
            const float v = C[(bl*12 + n)*129 + col];
            s += v; mx = fmaxf(mx, v);
        }
        const float b  = b3[col];
        const long  ob = ((long)blockIdx.x*4 + bl) * 256;
        out[ob + col]       = s / 12.0f + b;   // bias after pool: valid for mean & max
        out[ob + 128 + col] = mx + b;
    }
}

// Convert W1/W2/W3 (fp32, K x N) to fp16 transposed (N x K) in workspace.
__global__ void prep_weights(const float* __restrict__ W1,
                             const float* __restrict__ W2,
                             const float* __restrict__ W3,
                             _Float16* __restrict__ wt)
{
    const int tid = blockIdx.x * 256 + threadIdx.x;
    constexpr int N1 = 512*256, N2 = 256*256, N3 = 256*128;
    if (tid < N1) {
        const int o = tid >> 9, k = tid & 511;          // wt1: 256 x 512
        wt[tid] = (_Float16)W1[k*256 + o];
    } else if (tid < N1 + N2) {
        const int t = tid - N1;
        const int o = t >> 8, k = t & 255;              // wt2: 256 x 256
        wt[N1 + t] = (_Float16)W2[k*256 + o];
    } else if (tid < N1 + N2 + N3) {
        const int t = tid - N1 - N2;
        const int o = t >> 8, k = t & 255;              // wt3: 128 x 256
        wt[N1 + N2 + t] = (_Float16)W3[k*128 + o];      // W3 is (256,128): stride 128
    }
}

extern "C" void kernel_launch(void* const* d_in, const int* in_sizes, int n_in,
                              void* d_out, int out_size, void* d_ws, size_t ws_size,
                              hipStream_t stream)
{
    const float* x  = (const float*)d_in[0];
    const float* W1 = (const float*)d_in[1];
    const float* b1 = (const float*)d_in[2];
    const float* W2 = (const float*)d_in[3];
    const float* b2 = (const float*)d_in[4];
    const float* W3 = (const float*)d_in[5];
    const float* b3 = (const float*)d_in[6];
    float* out = (float*)d_out;

    // ws layout (halves): wt1 | wt2 | wt3   (hidden states live in LDS)
    _Float16* wt  = (_Float16*)d_ws;
    _Float16* wt1 = wt;
    _Float16* wt2 = wt + 512*256;
    _Float16* wt3 = wt + 512*256 + 256*256;

    prep_weights<<<896, 256, 0, stream>>>(W1, W2, W3, wt);
    gcn_fused<<<4096, 512, 0, stream>>>(x, wt1, b1, wt2, b2, wt3, b3, out);
}

// Round 4
// 602.166 us; speedup vs baseline: 1.3218x; 1.2381x over previous
//
#include <hip/hip_runtime.h>
#include <math.h>

typedef _Float16 f16x8 __attribute__((ext_vector_type(8)));
typedef _Float16 f16x2 __attribute__((ext_vector_type(2)));
typedef float    f32x4 __attribute__((ext_vector_type(4)));

// Fixed ECG graph. The 12-lead graph is TWO DISCONNECTED 6-node components:
// leads 0-5 (dense) and 6-11 (chain). dinv = 1/sqrt(deg), deg of a_eff=adj+2I.
namespace {
constexpr float kDinv[12] = {
    0.40824829046386302f, 0.37796447300922720f, 0.40824829046386302f,
    0.44721359549995794f, 0.5f, 0.5f,
    0.57735026918962576f, 0.5f, 0.5f, 0.5f, 0.5f, 0.57735026918962576f};

constexpr int ROWS  = 96;                  // 8 lead-groups of 12 per block
constexpr int AST   = 72;                  // A-tile row stride in halves
constexpr int AHALF = ROWS * AST;          // halves per A buffer (6912)
constexpr int ABYTES = 2 * AHALF * 2;      // 27648 (double-buffered)
constexpr int HST   = 258;                 // hidden row stride in halves
constexpr int HBYTES = ROWS * HST * 2;     // 49536
constexpr int SMEM   = ABYTES + HBYTES;    // 77184 B -> 2 blocks/CU
}

// LDS-only fence + raw barrier: global loads in flight (vmcnt) survive the
// barrier (unlike __syncthreads(), which drains vmcnt(0)).
__device__ __forceinline__ void barrier_keep_vmcnt()
{
    __builtin_amdgcn_sched_barrier(0);
    asm volatile("s_waitcnt lgkmcnt(0)" ::: "memory");
    __builtin_amdgcn_s_barrier();
    __builtin_amdgcn_sched_barrier(0);
}

// Load 6 leads of one cluster (pre-scaled by dinv) for k-chunk kc.
template<int K, bool SRC_LDS, bool CB>
__device__ __forceinline__ void load_y(const float* __restrict__ xrow,
                                       const _Float16* __restrict__ hs,
                                       int g, int f2, int kc, float2 (&y)[6])
{
    #pragma unroll
    for (int n = 0; n < 6; ++n) {
        const float d = kDinv[(CB ? 6 : 0) + n];
        if constexpr (!SRC_LDS) {
            const float* p = xrow + (long)n * K + kc * 64;   // xrow includes f2*2
            y[n].x = d * p[0];
            y[n].y = d * p[1];
        } else {
            const f16x2 h2 = *(const f16x2*)&hs[(g*12 + (CB?6:0) + n)*HST + kc*64 + f2*2];
            y[n].x = d * (float)h2.x;
            y[n].y = d * (float)h2.y;
        }
    }
}

// Mix the 6 rows of one cluster (formulas folded from the adjacency masks),
// store fp16 into the A staging buffer.
template<bool CB>
__device__ __forceinline__ void mix6(const float2 (&y)[6],
                                     _Float16* __restrict__ A, int g, int f2)
{
    float rx[6], ry[6];
    if constexpr (!CB) {               // leads 0-5
        rx[0] = 2.f*y[0].x + y[1].x + y[2].x + y[3].x + y[4].x;
        ry[0] = 2.f*y[0].y + y[1].y + y[2].y + y[3].y + y[4].y;
        rx[1] = 2.f*y[1].x + y[0].x + y[2].x + y[3].x + y[4].x + y[5].x;
        ry[1] = 2.f*y[1].y + y[0].y + y[2].y + y[3].y + y[4].y + y[5].y;
        rx[2] = 2.f*y[2].x + y[0].x + y[1].x + y[3].x + y[5].x;
        ry[2] = 2.f*y[2].y + y[0].y + y[1].y + y[3].y + y[5].y;
        rx[3] = 2.f*y[3].x + y[0].x + y[1].x + y[2].x;
        ry[3] = 2.f*y[3].y + y[0].y + y[1].y + y[2].y;
        rx[4] = 2.f*y[4].x + y[0].x + y[1].x;
        ry[4] = 2.f*y[4].y + y[0].y + y[1].y;
        rx[5] = 2.f*y[5].x + y[1].x + y[2].x;
        ry[5] = 2.f*y[5].y + y[1].y + y[2].y;
    } else {                           // leads 6-11 (chain)
        rx[0] = 2.f*y[0].x + y[1].x;
        ry[0] = 2.f*y[0].y + y[1].y;
        rx[1] = 2.f*y[1].x + y[0].x + y[2].x;
        ry[1] = 2.f*y[1].y + y[0].y + y[2].y;
        rx[2] = 2.f*y[2].x + y[1].x + y[3].x;
        ry[2] = 2.f*y[2].y + y[1].y + y[3].y;
        rx[3] = 2.f*y[3].x + y[2].x + y[4].x;
        ry[3] = 2.f*y[3].y + y[2].y + y[4].y;
        rx[4] = 2.f*y[4].x + y[3].x + y[5].x;
        ry[4] = 2.f*y[4].y + y[3].y + y[5].y;
        rx[5] = 2.f*y[5].x + y[4].x;
        ry[5] = 2.f*y[5].y + y[4].y;
    }
    #pragma unroll
    for (int i = 0; i < 6; ++i) {
        const float d = kDinv[(CB ? 6 : 0) + i];
        f16x2 h2;
        h2.x = (_Float16)(d * rx[i]);
        h2.y = (_Float16)(d * ry[i]);
        *(f16x2*)&A[(g*12 + (CB?6:0) + i)*AST + f2*2] = h2;
    }
}

// One pipelined chunk-iteration: issue bf[kc] -> (prefetch y[kc+2], mix chunk
// kc+1 into AbufW) -> MFMA chunk kc from AbufR -> ONE lgkm-only barrier.
// vmcnt ordering: waiting for yCons (oldest) leaves bf+yFill in flight;
// waiting for bf leaves yFill in flight.
template<int K, int N, bool SRC_LDS>
__device__ __forceinline__ void layer_iter(
    const float* __restrict__ xrow, const _Float16* __restrict__ hs,
    const _Float16* __restrict__ wtl,
    const _Float16* __restrict__ AbufR, _Float16* __restrict__ AbufW,
    bool cb, int g, int f2, int kc, int l15, int q,
    float2 (&yCons)[6], float2 (&yFill)[6],
    f32x4 (&acc)[6][N/128])
{
    constexpr int NTW = N / 128, KC = K / 64;

    // W fragments for this chunk, direct from global (L2-resident).
    f16x8 bf[2][NTW];
    #pragma unroll
    for (int ks = 0; ks < 2; ++ks)
        #pragma unroll
        for (int tn = 0; tn < NTW; ++tn)
            bf[ks][tn] = *(const f16x8*)(wtl + (long)tn*16*K + kc*64 + ks*32);

    if (cb) {
        if constexpr (!SRC_LDS)
            if (kc + 2 < KC) load_y<K,false,true>(xrow, hs, g, f2, kc+2, yFill);
        if (kc + 1 < KC) {
            if constexpr (SRC_LDS) load_y<K,true,true>(xrow, hs, g, f2, kc+1, yCons);
            mix6<true>(yCons, AbufW, g, f2);
        }
    } else {
        if constexpr (!SRC_LDS)
            if (kc + 2 < KC) load_y<K,false,false>(xrow, hs, g, f2, kc+2, yFill);
        if (kc + 1 < KC) {
            if constexpr (SRC_LDS) load_y<K,true,false>(xrow, hs, g, f2, kc+1, yCons);
            mix6<false>(yCons, AbufW, g, f2);
        }
    }

    #pragma unroll
    for (int ks = 0; ks < 2; ++ks)
        #pragma unroll
        for (int tm = 0; tm < 6; ++tm) {
            const f16x8 af = *(const f16x8*)&AbufR[(tm*16 + l15)*AST + ks*32 + q*8];
            #pragma unroll
            for (int tn = 0; tn < NTW; ++tn)
                acc[tm][tn] = __builtin_amdgcn_mfma_f32_16x16x32_f16(
                    af, bf[ks][tn], acc[tm][tn], 0, 0, 0);
        }
    barrier_keep_vmcnt();
}

// One GCN matmul: acc(96xN) = A_norm-mixed(src) @ W. Waves 0-3 mix cluster A
// (leads 0-5), waves 4-7 mix cluster B (leads 6-11) — no duplicate loads,
// wave-uniform branches. All 8 waves MFMA (wave owns 96 rows x N/8 cols).
template<int K, int N, bool SRC_LDS>
__device__ __forceinline__ void run_layer(
    const float* __restrict__ xg, const _Float16* __restrict__ hs,
    const _Float16* __restrict__ wt, _Float16* __restrict__ Abuf,
    long rowbase, int tid, f32x4 (&acc)[6][N/128])
{
    constexpr int NTW = N / 128, KC = K / 64;
    const int lane = tid & 63, wave = tid >> 6;
    const int l15 = lane & 15, q = lane >> 4;
    const bool cb = tid >= 256;
    const int mi = tid & 255, g = mi >> 5, f2 = mi & 31;

    const float* xrow = nullptr;
    if constexpr (!SRC_LDS)
        xrow = xg + (rowbase + g*12 + (cb ? 6 : 0)) * (long)K + f2*2;
    const _Float16* wtl = wt + (long)(wave*NTW*16 + l15) * K + q*8;

    #pragma unroll
    for (int a = 0; a < 6; ++a)
        #pragma unroll
        for (int b = 0; b < NTW; ++b)
            acc[a][b] = (f32x4){0.f, 0.f, 0.f, 0.f};

    float2 yA[6], yB[6];
    if (cb) {
        load_y<K,SRC_LDS,true>(xrow, hs, g, f2, 0, yA);
        if constexpr (!SRC_LDS) load_y<K,false,true>(xrow, hs, g, f2, 1, yB);
        mix6<true>(yA, Abuf, g, f2);
    } else {
        load_y<K,SRC_LDS,false>(xrow, hs, g, f2, 0, yA);
        if constexpr (!SRC_LDS) load_y<K,false,false>(xrow, hs, g, f2, 1, yB);
        mix6<false>(yA, Abuf, g, f2);
    }
    barrier_keep_vmcnt();

    for (int kc = 0; kc < KC; kc += 2) {   // static y-buffer parity (rule #20)
        layer_iter<K,N,SRC_LDS>(xrow, hs, wtl, Abuf,         Abuf + AHALF,
                                cb, g, f2, kc,     l15, q, yB, yA, acc);
        layer_iter<K,N,SRC_LDS>(xrow, hs, wtl, Abuf + AHALF, Abuf,
                                cb, g, f2, kc + 1, l15, q, yA, yB, acc);
    }
}

// bias + relu, store fp16 hidden state into LDS.
template<int N>
__device__ __forceinline__ void store_h(
    f32x4 (&acc)[6][N/128], const float* __restrict__ bias,
    _Float16* __restrict__ H, int tid)
{
    constexpr int NTW = N / 128;
    const int lane = tid & 63, wave = tid >> 6;
    const int l15 = lane & 15, q = lane >> 4;
    float bcol[NTW];
    #pragma unroll
    for (int tn = 0; tn < NTW; ++tn) bcol[tn] = bias[wave*NTW*16 + tn*16 + l15];
    #pragma unroll
    for (int tm = 0; tm < 6; ++tm)
        #pragma unroll
        for (int tn = 0; tn < NTW; ++tn)
            #pragma unroll
            for (int r = 0; r < 4; ++r) {
                const int row = tm*16 + q*4 + r;
                const int col = wave*NTW*16 + tn*16 + l15;
                H[row*HST + col] = (_Float16)fmaxf(acc[tm][tn][r] + bcol[tn], 0.f);
            }
}

// Fully fused 3-layer GCN + pool; hidden states live in LDS.
// Block = 96 rows (8 batch groups of 12 leads), grid 2048, 8 waves.
__global__ __launch_bounds__(512, 4)
void gcn_fused(const float* __restrict__ x,
               const _Float16* __restrict__ wt1, const float* __restrict__ b1,
               const _Float16* __restrict__ wt2, const float* __restrict__ b2,
               const _Float16* __restrict__ wt3, const float* __restrict__ b3,
               float* __restrict__ out)
{
    __shared__ __align__(16) char smem[SMEM];
    _Float16* Abuf = (_Float16*)smem;
    _Float16* Hbuf = (_Float16*)(smem + ABYTES);

    const int tid = threadIdx.x;
    const long rowbase = (long)blockIdx.x * ROWS;

    f32x4 acc[6][2];
    run_layer<512, 256, false>(x, nullptr, wt1, Abuf, rowbase, tid, acc);
    store_h<256>(acc, b1, Hbuf, tid);
    __syncthreads();

    run_layer<256, 256, true>(nullptr, Hbuf, wt2, Abuf, rowbase, tid, acc);
    store_h<256>(acc, b2, Hbuf, tid);
    __syncthreads();

    f32x4 acc3[6][1];
    run_layer<256, 128, true>(nullptr, Hbuf, wt3, Abuf, rowbase, tid, acc3);

    // Pool mean/max over the 12 leads of each batch group. Staging buffers are
    // dead after the final barrier -> reuse smem as float C[96][129].
    float* C = (float*)smem;
    {
        const int lane = tid & 63, wave = tid >> 6;
        const int l15 = lane & 15, q = lane >> 4;
        #pragma unroll
        for (int tm = 0; tm < 6; ++tm)
            #pragma unroll
            for (int r = 0; r < 4; ++r)
                C[(tm*16 + q*4 + r)*129 + wave*16 + l15] = acc3[tm][0][r];
    }
    __syncthreads();
    #pragma unroll
    for (int p = 0; p < 2; ++p) {
        const int idx = tid + p*512;           // 8 groups x 128 cols = 1024
        const int bl  = idx >> 7;
        const int col = idx & 127;
        float s = 0.0f, mx = -INFINITY;
        #pragma unroll
        for (int n = 0; n < 12; ++n) {
            const float v = C[(bl*12 + n)*129 + col];
            s += v; mx = fmaxf(mx, v);
        }
        const float b  = b3[col];
        const long  ob = ((long)blockIdx.x*8 + bl) * 256;
        out[ob + col]       = s / 12.0f + b;   // bias after pool: valid for mean & max
        out[ob + 128 + col] = mx + b;
    }
}

// Convert W1/W2/W3 (fp32, K x N) to fp16 transposed (N x K) in workspace.
__global__ void prep_weights(const float* __restrict__ W1,
                             const float* __restrict__ W2,
                             const float* __restrict__ W3,
                             _Float16* __restrict__ wt)
{
    const int tid = blockIdx.x * 256 + threadIdx.x;
    constexpr int N1 = 512*256, N2 = 256*256, N3 = 256*128;
    if (tid < N1) {
        const int o = tid >> 9, k = tid & 511;          // wt1: 256 x 512
        wt[tid] = (_Float16)W1[k*256 + o];
    } else if (tid < N1 + N2) {
        const int t = tid - N1;
        const int o = t >> 8, k = t & 255;              // wt2: 256 x 256
        wt[N1 + t] = (_Float16)W2[k*256 + o];
    } else if (tid < N1 + N2 + N3) {
        const int t = tid - N1 - N2;
        const int o = t >> 8, k = t & 255;              // wt3: 128 x 256
        wt[N1 + N2 + t] = (_Float16)W3[k*128 + o];      // W3 is (256,128): stride 128
    }
}

extern "C" void kernel_launch(void* const* d_in, const int* in_sizes, int n_in,
                              void* d_out, int out_size, void* d_ws, size_t ws_size,
                              hipStream_t stream)
{
    const float* x  = (const float*)d_in[0];
    const float* W1 = (const float*)d_in[1];
    const float* b1 = (const float*)d_in[2];
    const float* W2 = (const float*)d_in[3];
    const float* b2 = (const float*)d_in[4];
    const float* W3 = (const float*)d_in[5];
    const float* b3 = (const float*)d_in[6];
    float* out = (float*)d_out;

    // ws layout (halves): wt1 | wt2 | wt3   (hidden states live in LDS)
    _Float16* wt  = (_Float16*)d_ws;
    _Float16* wt1 = wt;
    _Float16* wt2 = wt + 512*256;
    _Float16* wt3 = wt + 512*256 + 256*256;

    prep_weights<<<896, 256, 0, stream>>>(W1, W2, W3, wt);
    gcn_fused<<<2048, 512, 0, stream>>>(x, wt1, b1, wt2, b2, wt3, b3, out);
}